// Round 15
// baseline (76.541 us; speedup 1.0000x reference)
//
#include <hip/hip_runtime.h>

#define TPL_SIZE 16384
#define TPL_K 16
#define TPL_ND 5
#define TPL_BLK 512
#define TPL_PTS 2                                  // points per thread
#define TPL_SPAN (TPL_BLK * TPL_PTS)               // 1024 points per block
#define TPL_BPB (TPL_SIZE / TPL_SPAN)              // 16 blocks per batch
#define TPL_NXCD 8

// R15: 64 KB LDS table -> 2 blocks/CU (16 waves/CU, 4 waves/SIMD).
// Diagnosis: R10 rcp win + R11/R12/R14 nulls => latency-bound at 8 waves/CU,
// pinned by the 128 KB table. Fix: LDS entry = packed {px_u16|py_u16} ONLY
// (4 B); neighbor VALUES gather from global x instead -- per-batch x is
// 64 KB, L2-resident, ~200cy hits that the doubled occupancy hides.
// Grid 512 x 512 threads, 2 pts/thread; HBM traffic unchanged.
// __launch_bounds__(512,4) -> 128-VGPR cap (needed for 2 blocks/CU);
// scalar accumulation for low reg pressure. Spill tell = WRITE_SIZE.
// Kept: XCD remap (a batch's 16 blocks share one XCD's L2), depth-1
// edge/dist prefetch, rcp-pivot 5x5 GE solve (reciprocals reused).
__global__ __launch_bounds__(TPL_BLK, 4) void tp_lds_kernel(
    const float* __restrict__ x,
    const float* __restrict__ points,
    const int*   __restrict__ edge_index,
    const float* __restrict__ dtp,
    const float* __restrict__ dist,
    const float* __restrict__ weight,
    float* __restrict__ out)
{
    extern __shared__ unsigned lds_xy[];   // [TPL_SIZE] = 64 KB

    const int tid = threadIdx.x;
    const int blk = blockIdx.x;

    // blk -> (batch, chunk): xcd = blk&7 ; 4 batches per XCD ; 16 chunks/batch
    const int xcd   = blk & (TPL_NXCD - 1);
    const int idx   = blk >> 3;                      // [0,64)
    const int batch = xcd * 4 + (idx >> 4);          // [0,32)
    const int chunk = idx & (TPL_BPB - 1);           // [0,16)

    const size_t bb   = (size_t)batch * TPL_SIZE;
    const size_t base = bb + chunk * TPL_SPAN;

    const float* xb = x + bb;

    // ---- issue point 0's streaming loads FIRST (hide under staging) ----
    int4   ci[4];
    float4 cw[4];
    {
        const int4*   ei = reinterpret_cast<const int4*>(edge_index + (base + tid) * TPL_K);
        const float4* dw = reinterpret_cast<const float4*>(dist      + (base + tid) * TPL_K);
        ci[0] = ei[0]; ci[1] = ei[1]; ci[2] = ei[2]; ci[3] = ei[3];
        cw[0] = dw[0]; cw[1] = dw[1]; cw[2] = dw[2]; cw[3] = dw[3];
    }

    // ---- stage packed xy (4 B/entry) into LDS: 16 coalesced iters ----
    {
        const float4* pb4 = reinterpret_cast<const float4*>(points + bb * 2);
        uint2* lds2 = reinterpret_cast<uint2*>(lds_xy);
        #pragma unroll
        for (int k = 0; k < TPL_SIZE / (2 * TPL_BLK); ++k) {   // 16 iters
            int g = k * TPL_BLK + tid;        // entries 2g, 2g+1
            float4 pp = pb4[g];
            unsigned ux0 = (unsigned)(pp.x * 65536.0f);
            unsigned uy0 = (unsigned)(pp.y * 65536.0f);
            unsigned ux1 = (unsigned)(pp.z * 65536.0f);
            unsigned uy1 = (unsigned)(pp.w * 65536.0f);
            if (ux0 > 65535u) ux0 = 65535u;
            if (uy0 > 65535u) uy0 = 65535u;
            if (ux1 > 65535u) ux1 = 65535u;
            if (uy1 > 65535u) uy1 = 65535u;
            uint2 wv;
            wv.x = ux0 | (uy0 << 16);
            wv.y = ux1 | (uy1 << 16);
            lds2[g] = wv;
        }
    }
    __syncthreads();

    const float wt0 = weight[0], wt1 = weight[1], wt2 = weight[2],
                wt3 = weight[3], wt4 = weight[4];
    const float dtv = dtp[0];

    #pragma unroll
    for (int p = 0; p < TPL_PTS; ++p) {
        const int    s   = chunk * TPL_SPAN + p * TPL_BLK + tid;
        const size_t row = base + p * TPL_BLK + tid;

        // self: xy from LDS (same quantization as neighbors), value from x
        unsigned se = lds_xy[s];
        const int sx = (int)(se & 0xffffu);
        const int sy = (int)(se >> 16);
        const float sv = xb[s];

        int ids[TPL_K] = {ci[0].x, ci[0].y, ci[0].z, ci[0].w,
                          ci[1].x, ci[1].y, ci[1].z, ci[1].w,
                          ci[2].x, ci[2].y, ci[2].z, ci[2].w,
                          ci[3].x, ci[3].y, ci[3].z, ci[3].w};
        float wgt[TPL_K] = {cw[0].x, cw[0].y, cw[0].z, cw[0].w,
                            cw[1].x, cw[1].y, cw[1].z, cw[1].w,
                            cw[2].x, cw[2].y, cw[2].z, cw[2].w,
                            cw[3].x, cw[3].y, cw[3].z, cw[3].w};

        // gather: xy from LDS, values from global x (L2-resident, 64 KB/batch)
        unsigned nxy[TPL_K];
        float    nv[TPL_K];
        #pragma unroll
        for (int t = 0; t < TPL_K; ++t) nxy[t] = lds_xy[ids[t]];
        #pragma unroll
        for (int t = 0; t < TPL_K; ++t) nv[t] = xb[ids[t]];

        // issue next point's streaming loads; latency hides under accum+solve
        if (p < TPL_PTS - 1) {
            const size_t rown = base + (p + 1) * TPL_BLK + tid;
            const int4*   ei = reinterpret_cast<const int4*>(edge_index + rown * TPL_K);
            const float4* dw = reinterpret_cast<const float4*>(dist      + rown * TPL_K);
            #pragma unroll
            for (int q = 0; q < 4; ++q) { ci[q] = ei[q]; cw[q] = dw[q]; }
        }

        float ata[15], atb[TPL_ND];
        #pragma unroll
        for (int i = 0; i < 15; ++i) ata[i] = 0.0f;
        #pragma unroll
        for (int i = 0; i < TPL_ND; ++i) atb[i] = 0.0f;

        #pragma unroll
        for (int t = 0; t < TPL_K; ++t) {
            float w = wgt[t];
            int dxi = (int)(nxy[t] & 0xffffu) - sx;
            int dyi = (int)(nxy[t] >> 16)     - sy;
            float dx = (float)dxi * 0x1p-16f;
            float dy = (float)dyi * 0x1p-16f;
            float a[TPL_ND];
            a[0] = dx * w;
            a[1] = dy * w;
            a[2] = 0.5f * dx * dx * w;
            a[3] = dx * dy * w;
            a[4] = 0.5f * dy * dy * w;
            float bwv = (nv[t] - sv) * w;
            int c = 0;
            #pragma unroll
            for (int i = 0; i < TPL_ND; ++i) {
                #pragma unroll
                for (int j = i; j < TPL_ND; ++j) ata[c++] += a[i] * a[j];
                atb[i] += a[i] * bwv;
            }
        }

        // 5x5 SPD solve, fully unrolled GE; rcp pivots reused in back-sub
        float M[TPL_ND][TPL_ND], r[TPL_ND], pinv[TPL_ND];
        {
            int c = 0;
            #pragma unroll
            for (int i = 0; i < TPL_ND; ++i) {
                #pragma unroll
                for (int j = i; j < TPL_ND; ++j) { M[i][j] = ata[c]; M[j][i] = ata[c]; ++c; }
                r[i] = atb[i];
                M[i][i] += 1e-6f;
            }
        }
        #pragma unroll
        for (int i = 0; i < TPL_ND; ++i) {
            float inv = __builtin_amdgcn_rcpf(M[i][i]);
            pinv[i] = inv;
            #pragma unroll
            for (int j = i + 1; j < TPL_ND; ++j) {
                float f = M[j][i] * inv;
                #pragma unroll
                for (int cc = i + 1; cc < TPL_ND; ++cc) M[j][cc] -= f * M[i][cc];
                r[j] -= f * r[i];
            }
        }
        float sol[TPL_ND];
        #pragma unroll
        for (int i = TPL_ND - 1; i >= 0; --i) {
            float sv2 = r[i];
            #pragma unroll
            for (int cc = i + 1; cc < TPL_ND; ++cc) sv2 -= M[i][cc] * sol[cc];
            sol[i] = sv2 * pinv[i];
        }

        float du = sol[0] * wt0 + sol[1] * wt1 + sol[2] * wt2
                 + sol[3] * wt3 + sol[4] * wt4;
        out[row] = sv + dtv * du;
    }
}

extern "C" void kernel_launch(void* const* d_in, const int* in_sizes, int n_in,
                              void* d_out, int out_size, void* d_ws, size_t ws_size,
                              hipStream_t stream) {
    const float* x          = (const float*)d_in[0];
    const float* points     = (const float*)d_in[1];
    const int*   edge_index = (const int*)d_in[2];
    const float* dtp        = (const float*)d_in[3];
    const float* dist       = (const float*)d_in[4];
    const float* weight     = (const float*)d_in[5];
    float* out = (float*)d_out;

    int total = out_size;                    // B * SIZE = 524288
    int grid  = total / TPL_SPAN;            // 512 blocks (16 per batch)
    size_t lds_bytes = (size_t)TPL_SIZE * sizeof(unsigned);  // 64 KB

    tp_lds_kernel<<<grid, TPL_BLK, lds_bytes, stream>>>(
        x, points, edge_index, dtp, dist, weight, out);
}

// Round 16
// 35.210 us; speedup vs baseline: 2.1738x; 2.1738x over previous
//
#include <hip/hip_runtime.h>

#define TPL_SIZE 16384
#define TPL_K 16
#define TPL_ND 5
#define TPL_BLK 512
#define TPL_PTS 2                                  // points per thread
#define TPL_SPAN (TPL_BLK * TPL_PTS)               // 1024 points per block
#define TPL_BPB (TPL_SIZE / TPL_SPAN)              // 16 blocks per batch
#define TPL_NXCD 8

// R16 = R15 retried with the CORRECT launch bounds.
// Compiler rule (R5/R6/R13/R15): VGPR cap = 256/min_waves_per_EU.
//   (512,4) -> 64 VGPR -> spill (R15's 129 MB WRITE_SIZE, 76 us).
//   (512,2) -> 128 VGPR -> fits. And 128 VGPR still ALLOWS 4 waves/EU
// (occupancy halves at 64/128/256), so with the 64 KB xy-only table
// (2 blocks/CU) we can reach 16 waves/CU = 2x today's occupancy.
// Structure: LDS = packed {px_u16|py_u16} (4 B/entry, 64 KB/batch);
// neighbor VALUES gather from global x (64 KB/batch, L2-resident ~200cy
// -- exactly what the doubled occupancy is there to hide). Value gathers
// issue BEFORE the LDS xy gathers (longest latency first).
// Kept: XCD remap (a batch's 16 blocks share one XCD L2), depth-1
// edge/dist prefetch, rcp-pivot 5x5 GE solve.
__global__ __launch_bounds__(TPL_BLK, 2) void tp_lds_kernel(
    const float* __restrict__ x,
    const float* __restrict__ points,
    const int*   __restrict__ edge_index,
    const float* __restrict__ dtp,
    const float* __restrict__ dist,
    const float* __restrict__ weight,
    float* __restrict__ out)
{
    extern __shared__ unsigned lds_xy[];   // [TPL_SIZE] = 64 KB

    const int tid = threadIdx.x;
    const int blk = blockIdx.x;

    // blk -> (batch, chunk): xcd = blk&7 ; 4 batches per XCD ; 16 chunks/batch
    const int xcd   = blk & (TPL_NXCD - 1);
    const int idx   = blk >> 3;                      // [0,64)
    const int batch = xcd * 4 + (idx >> 4);          // [0,32)
    const int chunk = idx & (TPL_BPB - 1);           // [0,16)

    const size_t bb   = (size_t)batch * TPL_SIZE;
    const size_t base = bb + chunk * TPL_SPAN;

    const float* xb = x + bb;

    // ---- issue point 0's streaming loads FIRST (hide under staging) ----
    int4   ci[4];
    float4 cw[4];
    {
        const int4*   ei = reinterpret_cast<const int4*>(edge_index + (base + tid) * TPL_K);
        const float4* dw = reinterpret_cast<const float4*>(dist      + (base + tid) * TPL_K);
        ci[0] = ei[0]; ci[1] = ei[1]; ci[2] = ei[2]; ci[3] = ei[3];
        cw[0] = dw[0]; cw[1] = dw[1]; cw[2] = dw[2]; cw[3] = dw[3];
    }

    // ---- stage packed xy (4 B/entry) into LDS: 16 coalesced iters ----
    {
        const float4* pb4 = reinterpret_cast<const float4*>(points + bb * 2);
        uint2* lds2 = reinterpret_cast<uint2*>(lds_xy);
        #pragma unroll
        for (int k = 0; k < TPL_SIZE / (2 * TPL_BLK); ++k) {   // 16 iters
            int g = k * TPL_BLK + tid;        // entries 2g, 2g+1
            float4 pp = pb4[g];
            unsigned ux0 = (unsigned)(pp.x * 65536.0f);
            unsigned uy0 = (unsigned)(pp.y * 65536.0f);
            unsigned ux1 = (unsigned)(pp.z * 65536.0f);
            unsigned uy1 = (unsigned)(pp.w * 65536.0f);
            if (ux0 > 65535u) ux0 = 65535u;
            if (uy0 > 65535u) uy0 = 65535u;
            if (ux1 > 65535u) ux1 = 65535u;
            if (uy1 > 65535u) uy1 = 65535u;
            uint2 wv;
            wv.x = ux0 | (uy0 << 16);
            wv.y = ux1 | (uy1 << 16);
            lds2[g] = wv;
        }
    }
    __syncthreads();

    const float wt0 = weight[0], wt1 = weight[1], wt2 = weight[2],
                wt3 = weight[3], wt4 = weight[4];
    const float dtv = dtp[0];

    #pragma unroll
    for (int p = 0; p < TPL_PTS; ++p) {
        const int    s   = chunk * TPL_SPAN + p * TPL_BLK + tid;
        const size_t row = base + p * TPL_BLK + tid;

        int ids[TPL_K] = {ci[0].x, ci[0].y, ci[0].z, ci[0].w,
                          ci[1].x, ci[1].y, ci[1].z, ci[1].w,
                          ci[2].x, ci[2].y, ci[2].z, ci[2].w,
                          ci[3].x, ci[3].y, ci[3].z, ci[3].w};
        float wgt[TPL_K] = {cw[0].x, cw[0].y, cw[0].z, cw[0].w,
                            cw[1].x, cw[1].y, cw[1].z, cw[1].w,
                            cw[2].x, cw[2].y, cw[2].z, cw[2].w,
                            cw[3].x, cw[3].y, cw[3].z, cw[3].w};

        // global value gathers FIRST (longest latency: L2 ~200cy)
        float nv[TPL_K];
        #pragma unroll
        for (int t = 0; t < TPL_K; ++t) nv[t] = xb[ids[t]];
        const float sv = xb[s];

        // then LDS xy gathers
        unsigned nxy[TPL_K];
        #pragma unroll
        for (int t = 0; t < TPL_K; ++t) nxy[t] = lds_xy[ids[t]];
        unsigned se = lds_xy[s];
        const int sx = (int)(se & 0xffffu);
        const int sy = (int)(se >> 16);

        // issue next point's streaming loads; latency hides under accum+solve
        if (p < TPL_PTS - 1) {
            const size_t rown = base + (p + 1) * TPL_BLK + tid;
            const int4*   ei = reinterpret_cast<const int4*>(edge_index + rown * TPL_K);
            const float4* dw = reinterpret_cast<const float4*>(dist      + rown * TPL_K);
            #pragma unroll
            for (int q = 0; q < 4; ++q) { ci[q] = ei[q]; cw[q] = dw[q]; }
        }

        float ata[15], atb[TPL_ND];
        #pragma unroll
        for (int i = 0; i < 15; ++i) ata[i] = 0.0f;
        #pragma unroll
        for (int i = 0; i < TPL_ND; ++i) atb[i] = 0.0f;

        #pragma unroll
        for (int t = 0; t < TPL_K; ++t) {
            float w = wgt[t];
            int dxi = (int)(nxy[t] & 0xffffu) - sx;
            int dyi = (int)(nxy[t] >> 16)     - sy;
            float dx = (float)dxi * 0x1p-16f;
            float dy = (float)dyi * 0x1p-16f;
            float a[TPL_ND];
            a[0] = dx * w;
            a[1] = dy * w;
            a[2] = 0.5f * dx * dx * w;
            a[3] = dx * dy * w;
            a[4] = 0.5f * dy * dy * w;
            float bwv = (nv[t] - sv) * w;
            int c = 0;
            #pragma unroll
            for (int i = 0; i < TPL_ND; ++i) {
                #pragma unroll
                for (int j = i; j < TPL_ND; ++j) ata[c++] += a[i] * a[j];
                atb[i] += a[i] * bwv;
            }
        }

        // 5x5 SPD solve, fully unrolled GE; rcp pivots reused in back-sub
        float M[TPL_ND][TPL_ND], r[TPL_ND], pinv[TPL_ND];
        {
            int c = 0;
            #pragma unroll
            for (int i = 0; i < TPL_ND; ++i) {
                #pragma unroll
                for (int j = i; j < TPL_ND; ++j) { M[i][j] = ata[c]; M[j][i] = ata[c]; ++c; }
                r[i] = atb[i];
                M[i][i] += 1e-6f;
            }
        }
        #pragma unroll
        for (int i = 0; i < TPL_ND; ++i) {
            float inv = __builtin_amdgcn_rcpf(M[i][i]);
            pinv[i] = inv;
            #pragma unroll
            for (int j = i + 1; j < TPL_ND; ++j) {
                float f = M[j][i] * inv;
                #pragma unroll
                for (int cc = i + 1; cc < TPL_ND; ++cc) M[j][cc] -= f * M[i][cc];
                r[j] -= f * r[i];
            }
        }
        float sol[TPL_ND];
        #pragma unroll
        for (int i = TPL_ND - 1; i >= 0; --i) {
            float sv2 = r[i];
            #pragma unroll
            for (int cc = i + 1; cc < TPL_ND; ++cc) sv2 -= M[i][cc] * sol[cc];
            sol[i] = sv2 * pinv[i];
        }

        float du = sol[0] * wt0 + sol[1] * wt1 + sol[2] * wt2
                 + sol[3] * wt3 + sol[4] * wt4;
        out[row] = sv + dtv * du;
    }
}

extern "C" void kernel_launch(void* const* d_in, const int* in_sizes, int n_in,
                              void* d_out, int out_size, void* d_ws, size_t ws_size,
                              hipStream_t stream) {
    const float* x          = (const float*)d_in[0];
    const float* points     = (const float*)d_in[1];
    const int*   edge_index = (const int*)d_in[2];
    const float* dtp        = (const float*)d_in[3];
    const float* dist       = (const float*)d_in[4];
    const float* weight     = (const float*)d_in[5];
    float* out = (float*)d_out;

    int total = out_size;                    // B * SIZE = 524288
    int grid  = total / TPL_SPAN;            // 512 blocks (16 per batch)
    size_t lds_bytes = (size_t)TPL_SIZE * sizeof(unsigned);  // 64 KB

    tp_lds_kernel<<<grid, TPL_BLK, lds_bytes, stream>>>(
        x, points, edge_index, dtp, dist, weight, out);
}

// Round 17
// 21.137 us; speedup vs baseline: 3.6212x; 1.6658x over previous
//
#include <hip/hip_runtime.h>

#define TPL_SIZE 16384
#define TPL_K 16
#define TPL_ND 5
#define TPL_BLK 512
#define TPL_PTS 4                                  // points per thread
#define TPL_SPAN (TPL_BLK * TPL_PTS)               // 2048 points per block
#define TPL_BPB (TPL_SIZE / TPL_SPAN)              // 8 blocks per batch
#define TPL_NXCD 8

typedef __attribute__((ext_vector_type(2))) float f32x2;

// FINAL (R17) = R11 structure, the measured best (21.04 us), restored after
// R12-R16 exploration all regressed or nulled. Ledger:
//   WINS: full-batch u16-packed LDS table (R7), XCD-aware block remap so a
//   batch's 8 blocks share one XCD's L2 (R8, -4us), v_rcp_f32 pivots reused
//   in back-sub (R10, -2.3us), 512-thread blocks to avoid the 64-VGPR
//   ceiling of 1024-thread blocks (R7; R5/R6/R13 spilled 60-110 MB).
//   CLOSED BRANCHES: op-count cuts null (R11), pair-packed solve null (R12),
//   global_load_lds DMA staging worse (R14), 64KB-table + L2 value gathers
//   worse even at 2 blocks/CU (R15/R16: scattered L2 requests cost more
//   than doubled occupancy buys). Value gathers MUST be LDS-resident;
//   the 128 KB table pins 1 block/CU = 8 waves -> latency plateau at
//   ~2x the ~10.5us streaming floor (VALU ~22%, HBM ~35%, neither bound).
// Only change vs R11: id masks dropped (ids guaranteed in [0,16384)).
__global__ __launch_bounds__(TPL_BLK, 2) void tp_lds_kernel(
    const float* __restrict__ x,
    const float* __restrict__ points,
    const int*   __restrict__ edge_index,
    const float* __restrict__ dtp,
    const float* __restrict__ dist,
    const float* __restrict__ weight,
    float* __restrict__ out)
{
    extern __shared__ uint2 lds_pv[];   // [TPL_SIZE] = 128 KB

    const int tid = threadIdx.x;
    const int blk = blockIdx.x;

    // blk -> (batch, chunk): xcd = blk&7 ; 4 batches per XCD
    const int xcd   = blk & (TPL_NXCD - 1);
    const int batch = xcd * 4 + (blk >> 6);          // [0,32)
    const int chunk = (blk >> 3) & (TPL_BPB - 1);    // [0,8)

    const size_t base = (size_t)batch * TPL_SIZE + chunk * TPL_SPAN;

    // ---- issue point 0's streaming loads FIRST (latency hides under staging)
    int4   ci[4];
    float4 cw[4];
    {
        const int4*   ei = reinterpret_cast<const int4*>(edge_index + (base + tid) * TPL_K);
        const float4* dw = reinterpret_cast<const float4*>(dist      + (base + tid) * TPL_K);
        ci[0] = ei[0]; ci[1] = ei[1]; ci[2] = ei[2]; ci[3] = ei[3];
        cw[0] = dw[0]; cw[1] = dw[1]; cw[2] = dw[2]; cw[3] = dw[3];
    }

    // ---- stage + quantize the whole batch table into LDS ----
    // 2 entries/thread/iter, fully coalesced: lane tid -> pb4[k*512+tid]
    {
        const float4* pb4 = reinterpret_cast<const float4*>(points + (size_t)batch * TPL_SIZE * 2);
        const float2* xb2 = reinterpret_cast<const float2*>(x + (size_t)batch * TPL_SIZE);
        uint4* lds4 = reinterpret_cast<uint4*>(lds_pv);
        #pragma unroll
        for (int k = 0; k < TPL_SIZE / (2 * TPL_BLK); ++k) {   // 16 iters
            int g = k * TPL_BLK + tid;        // pair-group index
            float4 pp = pb4[g];               // points for entries 2g, 2g+1
            float2 xv = xb2[g];               // values for entries 2g, 2g+1
            unsigned ux0 = (unsigned)(pp.x * 65536.0f);
            unsigned uy0 = (unsigned)(pp.y * 65536.0f);
            unsigned ux1 = (unsigned)(pp.z * 65536.0f);
            unsigned uy1 = (unsigned)(pp.w * 65536.0f);
            if (ux0 > 65535u) ux0 = 65535u;
            if (uy0 > 65535u) uy0 = 65535u;
            if (ux1 > 65535u) ux1 = 65535u;
            if (uy1 > 65535u) uy1 = 65535u;
            uint4 wv;
            wv.x = ux0 | (uy0 << 16);
            wv.y = __float_as_uint(xv.x);
            wv.z = ux1 | (uy1 << 16);
            wv.w = __float_as_uint(xv.y);
            lds4[g] = wv;
        }
    }
    __syncthreads();

    const float wt0 = weight[0], wt1 = weight[1], wt2 = weight[2],
                wt3 = weight[3], wt4 = weight[4];
    const float dtv = dtp[0];

    #pragma unroll
    for (int p = 0; p < TPL_PTS; ++p) {
        // prefetch next point's edge/dist while computing this one
        int4   ni[4];
        float4 nw[4];
        if (p < TPL_PTS - 1) {
            const size_t rown = base + (p + 1) * TPL_BLK + tid;
            const int4*   ei = reinterpret_cast<const int4*>(edge_index + rown * TPL_K);
            const float4* dw = reinterpret_cast<const float4*>(dist      + rown * TPL_K);
            ni[0] = ei[0]; ni[1] = ei[1]; ni[2] = ei[2]; ni[3] = ei[3];
            nw[0] = dw[0]; nw[1] = dw[1]; nw[2] = dw[2]; nw[3] = dw[3];
        }

        const int    s   = chunk * TPL_SPAN + p * TPL_BLK + tid;
        const size_t row = base + p * TPL_BLK + tid;

        // self point from LDS (same quantization as neighbors)
        uint2 se = lds_pv[s];
        const int sx = (int)(se.x & 0xffffu);
        const int sy = (int)(se.x >> 16);
        const float sv = __uint_as_float(se.y);

        int ids[TPL_K] = {ci[0].x, ci[0].y, ci[0].z, ci[0].w,
                          ci[1].x, ci[1].y, ci[1].z, ci[1].w,
                          ci[2].x, ci[2].y, ci[2].z, ci[2].w,
                          ci[3].x, ci[3].y, ci[3].z, ci[3].w};
        float wgt[TPL_K] = {cw[0].x, cw[0].y, cw[0].z, cw[0].w,
                            cw[1].x, cw[1].y, cw[1].z, cw[1].w,
                            cw[2].x, cw[2].y, cw[2].z, cw[2].w,
                            cw[3].x, cw[3].y, cw[3].z, cw[3].w};

        uint2 nb[TPL_K];
        #pragma unroll
        for (int t = 0; t < TPL_K; ++t) nb[t] = lds_pv[ids[t]];

        // ---- packed accumulation: neighbors 2tt (lo) and 2tt+1 (hi) ----
        f32x2 ata2[15], atb2[TPL_ND];
        #pragma unroll
        for (int i = 0; i < 15; ++i) ata2[i] = (f32x2)0.0f;
        #pragma unroll
        for (int i = 0; i < TPL_ND; ++i) atb2[i] = (f32x2)0.0f;

        #pragma unroll
        for (int tt = 0; tt < TPL_K / 2; ++tt) {
            const int t0 = 2 * tt, t1 = 2 * tt + 1;
            int dxi0 = (int)(nb[t0].x & 0xffffu) - sx;
            int dyi0 = (int)(nb[t0].x >> 16)     - sy;
            int dxi1 = (int)(nb[t1].x & 0xffffu) - sx;
            int dyi1 = (int)(nb[t1].x >> 16)     - sy;
            f32x2 dx = (f32x2){(float)dxi0, (float)dxi1} * 0x1p-16f;
            f32x2 dy = (f32x2){(float)dyi0, (float)dyi1} * 0x1p-16f;
            f32x2 w  = {wgt[t0], wgt[t1]};
            f32x2 nv = {__uint_as_float(nb[t0].y), __uint_as_float(nb[t1].y)};
            f32x2 hw = w * 0.5f;
            f32x2 a[TPL_ND];
            a[0] = dx * w;
            a[1] = dy * w;
            a[2] = dx * dx * hw;
            a[3] = dx * dy * w;
            a[4] = dy * dy * hw;
            f32x2 bwv = (nv - sv) * w;
            int c = 0;
            #pragma unroll
            for (int i = 0; i < TPL_ND; ++i) {
                #pragma unroll
                for (int j = i; j < TPL_ND; ++j) { ata2[c] += a[i] * a[j]; ++c; }
                atb2[i] += a[i] * bwv;
            }
        }

        // horizontal reduce lo+hi
        float ata[15], atb[TPL_ND];
        #pragma unroll
        for (int i = 0; i < 15; ++i) ata[i] = ata2[i].x + ata2[i].y;
        #pragma unroll
        for (int i = 0; i < TPL_ND; ++i) atb[i] = atb2[i].x + atb2[i].y;

        // 5x5 SPD solve, fully unrolled GE; rcp pivots reused in back-sub
        float M[TPL_ND][TPL_ND], r[TPL_ND], pinv[TPL_ND];
        {
            int c = 0;
            #pragma unroll
            for (int i = 0; i < TPL_ND; ++i) {
                #pragma unroll
                for (int j = i; j < TPL_ND; ++j) { M[i][j] = ata[c]; M[j][i] = ata[c]; ++c; }
                r[i] = atb[i];
                M[i][i] += 1e-6f;
            }
        }
        #pragma unroll
        for (int i = 0; i < TPL_ND; ++i) {
            float inv = __builtin_amdgcn_rcpf(M[i][i]);
            pinv[i] = inv;
            #pragma unroll
            for (int j = i + 1; j < TPL_ND; ++j) {
                float f = M[j][i] * inv;
                #pragma unroll
                for (int cc = i + 1; cc < TPL_ND; ++cc) M[j][cc] -= f * M[i][cc];
                r[j] -= f * r[i];
            }
        }
        float sol[TPL_ND];
        #pragma unroll
        for (int i = TPL_ND - 1; i >= 0; --i) {
            float sv2 = r[i];
            #pragma unroll
            for (int cc = i + 1; cc < TPL_ND; ++cc) sv2 -= M[i][cc] * sol[cc];
            sol[i] = sv2 * pinv[i];
        }

        float du = sol[0] * wt0 + sol[1] * wt1 + sol[2] * wt2
                 + sol[3] * wt3 + sol[4] * wt4;
        out[row] = sv + dtv * du;

        // rotate pipeline (static indices only)
        if (p < TPL_PTS - 1) {
            #pragma unroll
            for (int q = 0; q < 4; ++q) { ci[q] = ni[q]; cw[q] = nw[q]; }
        }
    }
}

extern "C" void kernel_launch(void* const* d_in, const int* in_sizes, int n_in,
                              void* d_out, int out_size, void* d_ws, size_t ws_size,
                              hipStream_t stream) {
    const float* x          = (const float*)d_in[0];
    const float* points     = (const float*)d_in[1];
    const int*   edge_index = (const int*)d_in[2];
    const float* dtp        = (const float*)d_in[3];
    const float* dist       = (const float*)d_in[4];
    const float* weight     = (const float*)d_in[5];
    float* out = (float*)d_out;

    int total = out_size;                    // B * SIZE = 524288
    int grid  = total / TPL_SPAN;            // 256 blocks (8 per batch)
    size_t lds_bytes = (size_t)TPL_SIZE * sizeof(uint2);  // 128 KB

    tp_lds_kernel<<<grid, TPL_BLK, lds_bytes, stream>>>(
        x, points, edge_index, dtp, dist, weight, out);
}

// Round 18
// 20.278 us; speedup vs baseline: 3.7745x; 1.0423x over previous
//
#include <hip/hip_runtime.h>

#define TPL_SIZE 16384
#define TPL_K 16
#define TPL_ND 5
#define TPL_BLK 512
#define TPL_PTS 4                                  // points per thread
#define TPL_SPAN (TPL_BLK * TPL_PTS)               // 2048 points per block
#define TPL_BPB (TPL_SIZE / TPL_SPAN)              // 8 blocks per batch
#define TPL_NXCD 8

typedef __attribute__((ext_vector_type(2))) float f32x2;

// R18 = R17 (21.1 us converged structure) + CLEAN depth-2 edge/dist prefetch.
// Rationale: per-replay caches are wiped -> edge+dist (64 MB) streams from
// HBM (~9.3 us floor). Achieved is only ~3.1 TB/s because only 8 KB/wave is
// in flight and issue is bursty (no loads issued during solve). Depth-2
// doubles outstanding bytes (16 KB/wave) and halves burst gaps. R9's
// depth-2 regression was confounded with a strided (half-coalesced) staging
// rewrite; this keeps R17's coalesced staging byte-for-byte.
// Ledger unchanged: u16 LDS table (R7), XCD remap (R8), rcp solve (R10),
// 512-thread blocks / (512,2) -> 128-VGPR cap (R7/R16).
__global__ __launch_bounds__(TPL_BLK, 2) void tp_lds_kernel(
    const float* __restrict__ x,
    const float* __restrict__ points,
    const int*   __restrict__ edge_index,
    const float* __restrict__ dtp,
    const float* __restrict__ dist,
    const float* __restrict__ weight,
    float* __restrict__ out)
{
    extern __shared__ uint2 lds_pv[];   // [TPL_SIZE] = 128 KB

    const int tid = threadIdx.x;
    const int blk = blockIdx.x;

    // blk -> (batch, chunk): xcd = blk&7 ; 4 batches per XCD
    const int xcd   = blk & (TPL_NXCD - 1);
    const int batch = xcd * 4 + (blk >> 6);          // [0,32)
    const int chunk = (blk >> 3) & (TPL_BPB - 1);    // [0,8)

    const size_t base = (size_t)batch * TPL_SIZE + chunk * TPL_SPAN;

    // ---- depth-2 prologue: issue points 0 AND 1's streaming loads FIRST
    // (both hide under staging; 16 KB/wave in flight)
    int4   ci2[2][4];
    float4 cw2[2][4];
    #pragma unroll
    for (int d = 0; d < 2; ++d) {
        const size_t rw = base + d * TPL_BLK + tid;
        const int4*   ei = reinterpret_cast<const int4*>(edge_index + rw * TPL_K);
        const float4* dw = reinterpret_cast<const float4*>(dist      + rw * TPL_K);
        #pragma unroll
        for (int q = 0; q < 4; ++q) { ci2[d][q] = ei[q]; cw2[d][q] = dw[q]; }
    }

    // ---- stage + quantize the whole batch table into LDS ----
    // 2 entries/thread/iter, fully coalesced (identical to R17)
    {
        const float4* pb4 = reinterpret_cast<const float4*>(points + (size_t)batch * TPL_SIZE * 2);
        const float2* xb2 = reinterpret_cast<const float2*>(x + (size_t)batch * TPL_SIZE);
        uint4* lds4 = reinterpret_cast<uint4*>(lds_pv);
        #pragma unroll
        for (int k = 0; k < TPL_SIZE / (2 * TPL_BLK); ++k) {   // 16 iters
            int g = k * TPL_BLK + tid;        // pair-group index
            float4 pp = pb4[g];               // points for entries 2g, 2g+1
            float2 xv = xb2[g];               // values for entries 2g, 2g+1
            unsigned ux0 = (unsigned)(pp.x * 65536.0f);
            unsigned uy0 = (unsigned)(pp.y * 65536.0f);
            unsigned ux1 = (unsigned)(pp.z * 65536.0f);
            unsigned uy1 = (unsigned)(pp.w * 65536.0f);
            if (ux0 > 65535u) ux0 = 65535u;
            if (uy0 > 65535u) uy0 = 65535u;
            if (ux1 > 65535u) ux1 = 65535u;
            if (uy1 > 65535u) uy1 = 65535u;
            uint4 wv;
            wv.x = ux0 | (uy0 << 16);
            wv.y = __float_as_uint(xv.x);
            wv.z = ux1 | (uy1 << 16);
            wv.w = __float_as_uint(xv.y);
            lds4[g] = wv;
        }
    }
    __syncthreads();

    const float wt0 = weight[0], wt1 = weight[1], wt2 = weight[2],
                wt3 = weight[3], wt4 = weight[4];
    const float dtv = dtp[0];

    #pragma unroll
    for (int p = 0; p < TPL_PTS; ++p) {
        const int    s   = chunk * TPL_SPAN + p * TPL_BLK + tid;
        const size_t row = base + p * TPL_BLK + tid;

        // copy current slot to locals (p&1 is compile-time after unroll)
        int ids[TPL_K];
        float wgt[TPL_K];
        #pragma unroll
        for (int q = 0; q < 4; ++q) {
            ids[4*q+0] = ci2[p & 1][q].x;
            ids[4*q+1] = ci2[p & 1][q].y;
            ids[4*q+2] = ci2[p & 1][q].z;
            ids[4*q+3] = ci2[p & 1][q].w;
            wgt[4*q+0] = cw2[p & 1][q].x;
            wgt[4*q+1] = cw2[p & 1][q].y;
            wgt[4*q+2] = cw2[p & 1][q].z;
            wgt[4*q+3] = cw2[p & 1][q].w;
        }

        // refill the freed slot with point p+2's loads (keeps 2 points of
        // edge/dist in flight through the whole compute)
        if (p + 2 < TPL_PTS) {
            const size_t rw = base + (p + 2) * TPL_BLK + tid;
            const int4*   ei = reinterpret_cast<const int4*>(edge_index + rw * TPL_K);
            const float4* dw = reinterpret_cast<const float4*>(dist      + rw * TPL_K);
            #pragma unroll
            for (int q = 0; q < 4; ++q) { ci2[p & 1][q] = ei[q]; cw2[p & 1][q] = dw[q]; }
        }

        // self point from LDS (same quantization as neighbors)
        uint2 se = lds_pv[s];
        const int sx = (int)(se.x & 0xffffu);
        const int sy = (int)(se.x >> 16);
        const float sv = __uint_as_float(se.y);

        uint2 nb[TPL_K];
        #pragma unroll
        for (int t = 0; t < TPL_K; ++t) nb[t] = lds_pv[ids[t]];

        // ---- packed accumulation: neighbors 2tt (lo) and 2tt+1 (hi) ----
        f32x2 ata2[15], atb2[TPL_ND];
        #pragma unroll
        for (int i = 0; i < 15; ++i) ata2[i] = (f32x2)0.0f;
        #pragma unroll
        for (int i = 0; i < TPL_ND; ++i) atb2[i] = (f32x2)0.0f;

        #pragma unroll
        for (int tt = 0; tt < TPL_K / 2; ++tt) {
            const int t0 = 2 * tt, t1 = 2 * tt + 1;
            int dxi0 = (int)(nb[t0].x & 0xffffu) - sx;
            int dyi0 = (int)(nb[t0].x >> 16)     - sy;
            int dxi1 = (int)(nb[t1].x & 0xffffu) - sx;
            int dyi1 = (int)(nb[t1].x >> 16)     - sy;
            f32x2 dx = (f32x2){(float)dxi0, (float)dxi1} * 0x1p-16f;
            f32x2 dy = (f32x2){(float)dyi0, (float)dyi1} * 0x1p-16f;
            f32x2 w  = {wgt[t0], wgt[t1]};
            f32x2 nv = {__uint_as_float(nb[t0].y), __uint_as_float(nb[t1].y)};
            f32x2 hw = w * 0.5f;
            f32x2 a[TPL_ND];
            a[0] = dx * w;
            a[1] = dy * w;
            a[2] = dx * dx * hw;
            a[3] = dx * dy * w;
            a[4] = dy * dy * hw;
            f32x2 bwv = (nv - sv) * w;
            int c = 0;
            #pragma unroll
            for (int i = 0; i < TPL_ND; ++i) {
                #pragma unroll
                for (int j = i; j < TPL_ND; ++j) { ata2[c] += a[i] * a[j]; ++c; }
                atb2[i] += a[i] * bwv;
            }
        }

        // horizontal reduce lo+hi
        float ata[15], atb[TPL_ND];
        #pragma unroll
        for (int i = 0; i < 15; ++i) ata[i] = ata2[i].x + ata2[i].y;
        #pragma unroll
        for (int i = 0; i < TPL_ND; ++i) atb[i] = atb2[i].x + atb2[i].y;

        // 5x5 SPD solve, fully unrolled GE; rcp pivots reused in back-sub
        float M[TPL_ND][TPL_ND], r[TPL_ND], pinv[TPL_ND];
        {
            int c = 0;
            #pragma unroll
            for (int i = 0; i < TPL_ND; ++i) {
                #pragma unroll
                for (int j = i; j < TPL_ND; ++j) { M[i][j] = ata[c]; M[j][i] = ata[c]; ++c; }
                r[i] = atb[i];
                M[i][i] += 1e-6f;
            }
        }
        #pragma unroll
        for (int i = 0; i < TPL_ND; ++i) {
            float inv = __builtin_amdgcn_rcpf(M[i][i]);
            pinv[i] = inv;
            #pragma unroll
            for (int j = i + 1; j < TPL_ND; ++j) {
                float f = M[j][i] * inv;
                #pragma unroll
                for (int cc = i + 1; cc < TPL_ND; ++cc) M[j][cc] -= f * M[i][cc];
                r[j] -= f * r[i];
            }
        }
        float sol[TPL_ND];
        #pragma unroll
        for (int i = TPL_ND - 1; i >= 0; --i) {
            float sv2 = r[i];
            #pragma unroll
            for (int cc = i + 1; cc < TPL_ND; ++cc) sv2 -= M[i][cc] * sol[cc];
            sol[i] = sv2 * pinv[i];
        }

        float du = sol[0] * wt0 + sol[1] * wt1 + sol[2] * wt2
                 + sol[3] * wt3 + sol[4] * wt4;
        out[row] = sv + dtv * du;
    }
}

extern "C" void kernel_launch(void* const* d_in, const int* in_sizes, int n_in,
                              void* d_out, int out_size, void* d_ws, size_t ws_size,
                              hipStream_t stream) {
    const float* x          = (const float*)d_in[0];
    const float* points     = (const float*)d_in[1];
    const int*   edge_index = (const int*)d_in[2];
    const float* dtp        = (const float*)d_in[3];
    const float* dist       = (const float*)d_in[4];
    const float* weight     = (const float*)d_in[5];
    float* out = (float*)d_out;

    int total = out_size;                    // B * SIZE = 524288
    int grid  = total / TPL_SPAN;            // 256 blocks (8 per batch)
    size_t lds_bytes = (size_t)TPL_SIZE * sizeof(uint2);  // 128 KB

    tp_lds_kernel<<<grid, TPL_BLK, lds_bytes, stream>>>(
        x, points, edge_index, dtp, dist, weight, out);
}